// Round 1
// baseline (228.621 us; speedup 1.0000x reference)
//
#include <hip/hip_runtime.h>
#include <hip/hip_fp16.h>

// SparseEncoder4D: gather-GEMM-scatter sparse conv (1->8->8->1) + dense scatter.
// R7: MFMA restructure of layer 2. R6 counters: FETCH fixed (75 MB) but
// VALU-issue-bound (56% VALUBusy, ~214k VALU cyc/CU of scalar FMAs).
// out[N x 8] = Ghat[N x 648] x W[648 x 8] with Ghat[n][k*8+c] = bit ? h1[idx[n,k]][c] : 0.
// mfma_f32_16x16x32_f16: A-frag lane layout (m=lane&15, k=quad*8+j) means one
// 16 B h1-row gather IS the A-fragment (no transform). Exec-masked gathers:
// only bit-set AND in-slice lanes issue requests -> each active (n,k) gathered
// exactly once across NP=2 L2-resident slice passes. B = w2 f16 in B-layout
// (21.5 KB table, L2-resident), built inside k_h1b. Epilogue: relu * w_out +
// 16-lane shuffle reduce -> outf. part/k_fin deleted.
// R8: byte-identical resubmission of R7 — previous round was an MI355X
// container infra failure; re-establish the 230.2 us baseline + counters.

#define KK 81
#define CH 8
#define NP 2      // idx-range slice passes (1.2 MB table slice stays L2-resident)
#define NS 21     // K-slices of 32: ceil(648/32)
#define KP 84     // padded conv-k slots (4 per slice * 21)
#define TT 4
#define ZZ 32
#define YY 256
#define XX 256

typedef __attribute__((ext_vector_type(8))) _Float16 half8;  // 16 B
typedef __attribute__((ext_vector_type(4))) float f32x4;

// ---------------- layer 1 (feats==ones): h1 fp16 + bitsT + Btab -------------
// bitsT[w][n] bit (k&31) of word w=k>>5 = mask[n][k] (81-bit little-endian).
// Btab[s*64+l] = B-fragment for slice s, lane l: B[32s+8q+j][d=l&15] =
//   w2[4s+q][j][d] (zero for d>=8 or conv-k>=81).
__global__ __launch_bounds__(256) void k_h1b(const float* __restrict__ w1,
                                             const float* __restrict__ w2,
                                             const int* __restrict__ nbr_mask,
                                             half8* __restrict__ h1,
                                             unsigned* __restrict__ bitsT,
                                             half8* __restrict__ Btab, int n_total) {
    __shared__ int lm[256 * 27];  // 27.6 KB
    const int tid = threadIdx.x;
    const int n0 = blockIdx.x * 256;
    const int n = n0 + tid;

    if (blockIdx.x < NS && tid < 64) {   // build Btab (tiny, folded in)
        int s = blockIdx.x, q = tid >> 4, d = tid & 15;
        int kk = 4 * s + q;
        half8 b;
#pragma unroll
        for (int j = 0; j < CH; j++)
            b[j] = (d < CH && kk < KK) ? (_Float16)w2[(kk * CH + j) * CH + d]
                                       : (_Float16)0.f;
        Btab[s * 64 + tid] = b;
    }

    float acc[CH] = {0.f, 0.f, 0.f, 0.f, 0.f, 0.f, 0.f, 0.f};
    unsigned cb[3];
#pragma unroll
    for (int ch = 0; ch < 3; ch++) {
        // stage 27-k chunk, flat coalesced
#pragma unroll
        for (int j = 0; j < 27; j++) {
            int i = tid + j * 256;
            int r = i / 27, c = i - r * 27;
            int srcn = n0 + r; if (srcn >= n_total) srcn = n_total - 1;
            lm[i] = nbr_mask[(long)srcn * KK + ch * 27 + c];
        }
        __syncthreads();
        unsigned cbits = 0;
        const int* row = lm + tid * 27;   // bank stride 27 -> 2-way, free
#pragma unroll
        for (int kk = 0; kk < 27; kk++) {
            int m = row[kk];
            cbits |= (unsigned)(m & 1) << kk;
            float fm = (float)m;
            const float* wp = w1 + (ch * 27 + kk) * CH;  // wave-uniform s_load
#pragma unroll
            for (int c = 0; c < CH; c++) acc[c] += fm * wp[c];
        }
        cb[ch] = cbits;
        __syncthreads();
    }

    if (n < n_total) {
        half8 r;
#pragma unroll
        for (int c = 0; c < CH; c++) r[c] = (_Float16)fmaxf(acc[c], 0.f);
        h1[n] = r;
        bitsT[n]               = cb[0] | (cb[1] << 27);
        bitsT[n_total + n]     = (cb[1] >> 5) | (cb[2] << 22);
        bitsT[2 * n_total + n] = cb[2] >> 10;
    }
}

// ---------------- layer 2 + head: MFMA gather-GEMM --------------------------
// Block = 256 thr = 4 waves; each wave owns 16 rows; block covers 64 rows.
__global__ __launch_bounds__(256) void k_h2m(const half8* __restrict__ h1,
                                             const half8* __restrict__ Btab,
                                             const int* __restrict__ nbr_idx,
                                             const unsigned* __restrict__ bitsT,
                                             const float* __restrict__ w_out,
                                             float* __restrict__ outf,
                                             int n_total, int slice) {
    __shared__ unsigned sidx[64 * KP];   // 21.5 KB masked idx (sentinel = ~0u)
    __shared__ unsigned sbits[3 * 64];   // 768 B
    const int tid = threadIdx.x;
    const int n0 = blockIdx.x * 64;

    if (tid < 192) {
        int w = tid >> 6, r = tid & 63;
        int sn = n0 + r;
        sbits[w * 64 + r] = (sn < n_total) ? bitsT[(long)w * n_total + sn] : 0u;
    }
    __syncthreads();

    // stage masked idx: 64 rows x 84 slots = 5376 = 21*256 (coalesced over c)
#pragma unroll
    for (int j = 0; j < 21; j++) {
        int i = tid + j * 256;
        int r = i / KP, c = i - r * KP;
        unsigned v = 0xFFFFFFFFu;
        int sn = n0 + r;
        if (c < KK && sn < n_total) {
            unsigned bit = (sbits[(c >> 5) * 64 + r] >> (c & 31)) & 1u;
            if (bit) v = (unsigned)nbr_idx[(long)sn * KK + c];
        }
        sidx[i] = v;
    }
    __syncthreads();

    const int lane = tid & 63, wid = tid >> 6;
    const int m = lane & 15, q = lane >> 4;
    const int row_local = wid * 16 + m;
    const unsigned* myidx = sidx + row_local * KP;  // +4s+q per slice; 2-way banks
    const unsigned uslice = (unsigned)slice;

    f32x4 acc = {0.f, 0.f, 0.f, 0.f};
    for (int p = 0; p < NP; p++) {
        unsigned lo = (unsigned)(p * slice);
#pragma unroll 3
        for (int s = 0; s < NS; s++) {
            unsigned ix = myidx[4 * s + q];
            half8 a = {(_Float16)0.f, (_Float16)0.f, (_Float16)0.f, (_Float16)0.f,
                       (_Float16)0.f, (_Float16)0.f, (_Float16)0.f, (_Float16)0.f};
            if (ix - lo < uslice)        // exec-masked: inactive lanes issue no req
                a = h1[ix];              // 16 B gather IS the A-fragment
            half8 b = Btab[s * 64 + lane];  // coalesced, L2-resident 21.5 KB
            acc = __builtin_amdgcn_mfma_f32_16x16x32_f16(a, b, acc, 0, 0, 0);
        }
    }

    // C/D layout: col = lane&15, row = q*4 + reg. Reduce cols (relu * w_out).
    float wo = (m < CH) ? w_out[m] : 0.f;
    float v0 = fmaxf(acc[0], 0.f) * wo, v1 = fmaxf(acc[1], 0.f) * wo;
    float v2 = fmaxf(acc[2], 0.f) * wo, v3 = fmaxf(acc[3], 0.f) * wo;
#pragma unroll
    for (int off = 1; off < 16; off <<= 1) {
        v0 += __shfl_xor(v0, off, 16);
        v1 += __shfl_xor(v1, off, 16);
        v2 += __shfl_xor(v2, off, 16);
        v3 += __shfl_xor(v3, off, 16);
    }
    if (m == 0) {
        int gn = n0 + wid * 16 + q * 4;
        if (gn + 0 < n_total) outf[gn + 0] = v0;
        if (gn + 1 < n_total) outf[gn + 1] = v1;
        if (gn + 2 < n_total) outf[gn + 2] = v2;
        if (gn + 3 < n_total) outf[gn + 3] = v3;
    }
}

// ---------------- deterministic dense scatter -------------------------------
__device__ __forceinline__ int cell_of(const int* coords, const int* batch, int n) {
    int4 c = *(const int4*)(coords + 4 * n);  // (x, y, z, t)
    int b = batch[n];
    return (((b * TT + c.w) * ZZ + c.z) * YY + c.y) * XX + c.x;
}

__global__ __launch_bounds__(256) void k_scat_max(const int* __restrict__ coords,
                                                  const int* __restrict__ batch,
                                                  int* __restrict__ dsti, int n_total) {
    int n = blockIdx.x * blockDim.x + threadIdx.x;
    if (n >= n_total) return;
    atomicMax(dsti + cell_of(coords, batch, n), n + 1);  // winner = max n
}

__global__ __launch_bounds__(256) void k_scat_write(const int* __restrict__ coords,
                                                    const int* __restrict__ batch,
                                                    const float* __restrict__ outf,
                                                    int* dsti, float* dstf, int n_total) {
    int n = blockIdx.x * blockDim.x + threadIdx.x;
    if (n >= n_total) return;
    int cell = cell_of(coords, batch, n);
    if (dsti[cell] == n + 1) dstf[cell] = outf[n];
}

extern "C" void kernel_launch(void* const* d_in, const int* in_sizes, int n_in,
                              void* d_out, int out_size, void* d_ws, size_t ws_size,
                              hipStream_t stream) {
    const float* w1       = (const float*)d_in[1];
    const float* w2       = (const float*)d_in[2];
    const float* w_out    = (const float*)d_in[3];
    const int*   nbr_idx  = (const int*)d_in[4];
    const int*   nbr_mask = (const int*)d_in[5];
    const int*   coords   = (const int*)d_in[6];
    const int*   batch    = (const int*)d_in[7];

    int n_total = in_sizes[0];
    int slice = (n_total + NP - 1) / NP;

    // ws: h1 (N+1 fp16x8, 2.4 MB) | bitsT (3N u32, 1.8 MB) | outf (N f32) | Btab (21.5 KB)
    half8*    h1    = (half8*)d_ws;
    unsigned* bitsT = (unsigned*)((char*)d_ws + (size_t)(n_total + 1) * sizeof(half8));
    float*    outf  = (float*)((char*)bitsT + (size_t)3 * n_total * sizeof(unsigned));
    half8*    Btab  = (half8*)(outf + n_total);
    float*    out   = (float*)d_out;

    hipMemsetAsync(out, 0, (size_t)out_size * sizeof(float), stream);

    int nb = (n_total + 255) / 256;
    k_h1b<<<nb, 256, 0, stream>>>(w1, w2, nbr_mask, h1, bitsT, Btab, n_total);
    int nb2 = (n_total + 63) / 64;
    k_h2m<<<nb2, 256, 0, stream>>>(h1, Btab, nbr_idx, bitsT, w_out, outf, n_total, slice);
    k_scat_max<<<nb, 256, 0, stream>>>(coords, batch, (int*)out, n_total);
    k_scat_write<<<nb, 256, 0, stream>>>(coords, batch, outf, (int*)out, out, n_total);
}